// Round 3
// baseline (4435.110 us; speedup 1.0000x reference)
//
#include <hip/hip_runtime.h>
#include <hip/hip_bf16.h>
#include <math.h>

#define TT 64
#define BB 256
#define DD 512
#define HH 512

typedef __attribute__((ext_vector_type(8))) short bf16x8;
typedef __attribute__((ext_vector_type(4))) float f32x4;

__device__ __forceinline__ float sigmoidf_(float x){ return 1.f/(1.f+__expf(-x)); }

// ---- quantum pair helpers: amp s = lane + 64*r, r in 0..3 holds bits (7,6) ----
__device__ __forceinline__ void rx_pair(float&ra,float&ia,float&rb,float&ib,float c,float s){
  float r0=ra, i0=ia, r1=rb, i1=ib;
  ra = c*r0 + s*i1;  ia = c*i0 - s*r1;
  rb = s*i0 + c*r1;  ib = c*i1 - s*r0;
}
__device__ __forceinline__ void ry_pair(float&ra,float&ia,float&rb,float&ib,float c,float s){
  float r0=ra, i0=ia, r1=rb, i1=ib;
  ra = c*r0 - s*r1;  ia = c*i0 - s*i1;
  rb = s*r0 + c*r1;  ib = s*i0 + c*i1;
}
__device__ __forceinline__ void rz_amp(float&r,float&i,float c,float sg){
  float r0=r; r = c*r0 + sg*i; i = c*i - sg*r0;
}

// ---- one-time: pack pW2 (512x512 f32, [k][n]) into MFMA-B fragment-major bf16.
// frag = kk*32 + nf (kk: K/32 step, nf: 16-col group). Within frag, lane's 8 bf16:
// element j = pW2[kk*32 + (lane>>4)*8 + j][nf*16 + (lane&15)].
__global__ __launch_bounds__(64) void k0_pack(const float* __restrict__ pW2,
                                              __hip_bfloat16* __restrict__ W2p){
  const int frag = blockIdx.x;          // 0..511
  const int kk = frag >> 5, nf = frag & 31;
  const int lane = threadIdx.x;
  const int n  = nf*16 + (lane & 15);
  const int kb = kk*32 + (lane >> 4)*8;
  __hip_bfloat16 v[8];
  #pragma unroll
  for (int j=0;j<8;j++)
    v[j] = __float2bfloat16(pW2[(size_t)(kb+j)*HH + n]);
  *reinterpret_cast<uint4*>(W2p + ((size_t)frag*64 + lane)*8) =
      *reinterpret_cast<const uint4*>(v);
}

// ---- the whole QLSTM: one block = 4 batches for all 64 timesteps ----
__global__ __launch_bounds__(1024) void qlstm_all(
    const float* __restrict__ x,    // (T,B,D)
    const float* __restrict__ Wf, const float* __restrict__ Wi,
    const float* __restrict__ Wu, const float* __restrict__ Wo,
    const float* __restrict__ bfv, const float* __restrict__ biv,
    const float* __restrict__ buv, const float* __restrict__ bov,
    const float* __restrict__ qpf, const float* __restrict__ qpi,
    const float* __restrict__ qpu, const float* __restrict__ qpo,
    const float* __restrict__ pW1, const float* __restrict__ pb1,
    const __hip_bfloat16* __restrict__ W2p, const float* __restrict__ pb2,
    float* __restrict__ out)
{
  __shared__ __hip_bfloat16 H1s[16][512];   // [m=b_loc*4+g][k], 16B-chunk XOR swizzle by (m&7)
  __shared__ float hxs[4][512];             // hx for the block's 4 batches

  const int tid  = threadIdx.x;
  const int lane = tid & 63;
  const int w    = tid >> 6;            // wave 0..15
  const int b0   = blockIdx.x * 4;

  // phase-Q wave roles
  const int bq = w >> 2;                // batch-local 0..3
  const int g  = w & 3;                 // gate f,i,u,o
  const float* Wg   = (g==0)?Wf :(g==1)?Wi :(g==2)?Wu :Wo;
  const float* bias = (g==0)?bfv:(g==1)?biv:(g==2)?buv:bov;
  const float* qp   = (g==0)?qpf:(g==1)?qpi:(g==2)?qpu:qpo;

  // phase-G per-thread cell state: (batch-local lane>>4, n = w*32 + fn*16 + (lane&15))
  float cx0 = 0.f, cx1 = 0.f;
  const int gb   = lane >> 4;           // batch-local in epilogue
  const int ncol0 = w*32 + (lane & 15);
  const int ncol1 = ncol0 + 16;

  // zero hx
  if (tid < 2048/1)
  { hxs[(tid>>9)&3][tid & 511] = 0.f; }
  if (tid < 1024) { int t2 = tid + 1024; hxs[(t2>>9)&3][t2 & 511] = 0.f; }
  __syncthreads();

  for (int t=0; t<TT; ++t){
    // ================= Phase Q: angles + circuit + H1 row =================
    {
      float acc[8] = {0,0,0,0,0,0,0,0};
      const float* xrow = x + ((size_t)t*BB + b0 + bq)*DD;
      #pragma unroll
      for (int it=0; it<DD/64; ++it){
        const int k = lane + it*64;
        const float xv = xrow[k];
        const float4* wr = reinterpret_cast<const float4*>(Wg + (size_t)k*8);
        float4 w0 = wr[0], w1 = wr[1];
        acc[0]+=xv*w0.x; acc[1]+=xv*w0.y; acc[2]+=xv*w0.z; acc[3]+=xv*w0.w;
        acc[4]+=xv*w1.x; acc[5]+=xv*w1.y; acc[6]+=xv*w1.z; acc[7]+=xv*w1.w;
      }
      #pragma unroll
      for (int it=0; it<HH/64; ++it){
        const int k = lane + it*64;
        const float hv = hxs[bq][k];
        const float4* wr = reinterpret_cast<const float4*>(Wg + (size_t)(DD+k)*8);
        float4 w0 = wr[0], w1 = wr[1];
        acc[0]+=hv*w0.x; acc[1]+=hv*w0.y; acc[2]+=hv*w0.z; acc[3]+=hv*w0.w;
        acc[4]+=hv*w1.x; acc[5]+=hv*w1.y; acc[6]+=hv*w1.z; acc[7]+=hv*w1.w;
      }
      float th[8];
      #pragma unroll
      for (int q=0;q<8;q++){
        #pragma unroll
        for (int m=32;m;m>>=1) acc[q] += __shfl_xor(acc[q], m);
        th[q] = acc[q] + bias[q];
      }

      // statevector sim: 256 amps, lane holds s = lane + 64*r
      float re[4]={0.f,0.f,0.f,0.f}, im[4]={0.f,0.f,0.f,0.f};
      if (lane==0) re[0]=1.f;

      #pragma unroll
      for (int q=0;q<8;q++){
        float s,c; __sincosf(0.5f*th[q], &s, &c);
        if (q==0){
          rx_pair(re[0],im[0],re[2],im[2],c,s);
          rx_pair(re[1],im[1],re[3],im[3],c,s);
        } else if (q==1){
          rx_pair(re[0],im[0],re[1],im[1],c,s);
          rx_pair(re[2],im[2],re[3],im[3],c,s);
        } else {
          const int mask = 1<<(7-q);
          #pragma unroll
          for (int r=0;r<4;r++){
            float rp = __shfl_xor(re[r], mask);
            float ip = __shfl_xor(im[r], mask);
            re[r] = c*re[r] + s*ip;
            im[r] = c*im[r] - s*rp;
          }
        }
      }

      #pragma unroll
      for (int l=0;l<2;l++){
        #pragma unroll
        for (int q=0;q<8;q++){
          const float thy = qp[(l*8+q)*3 + 0];
          const float thz = qp[(l*8+q)*3 + 1];
          float s,c; __sincosf(0.5f*thy, &s, &c);
          if (q==0){
            ry_pair(re[0],im[0],re[2],im[2],c,s);
            ry_pair(re[1],im[1],re[3],im[3],c,s);
          } else if (q==1){
            ry_pair(re[0],im[0],re[1],im[1],c,s);
            ry_pair(re[2],im[2],re[3],im[3],c,s);
          } else {
            const int mask = 1<<(7-q);
            const float sg = (lane & mask) ? s : -s;
            #pragma unroll
            for (int r=0;r<4;r++){
              float rp = __shfl_xor(re[r], mask);
              float ip = __shfl_xor(im[r], mask);
              re[r] = c*re[r] + sg*rp;
              im[r] = c*im[r] + sg*ip;
            }
          }
          __sincosf(0.5f*thz, &s, &c);
          if (q==0){
            rz_amp(re[0],im[0],c, s); rz_amp(re[1],im[1],c, s);
            rz_amp(re[2],im[2],c,-s); rz_amp(re[3],im[3],c,-s);
          } else if (q==1){
            rz_amp(re[0],im[0],c, s); rz_amp(re[2],im[2],c, s);
            rz_amp(re[1],im[1],c,-s); rz_amp(re[3],im[3],c,-s);
          } else {
            const int mask = 1<<(7-q);
            const float sg = (lane & mask) ? -s : s;
            #pragma unroll
            for (int r=0;r<4;r++) rz_amp(re[r],im[r],c,sg);
          }
        }
        { float tr=re[2]; re[2]=re[3]; re[3]=tr;
          float ti=im[2]; im[2]=im[3]; im[3]=ti; }
        re[1]=__shfl_xor(re[1],32); im[1]=__shfl_xor(im[1],32);
        re[3]=__shfl_xor(re[3],32); im[3]=__shfl_xor(im[3],32);
        #pragma unroll
        for (int cq=2;cq<7;cq++){
          const int cbit = 1<<(7-cq), tbit = 1<<(6-cq);
          const bool sw = (lane & cbit) != 0;
          #pragma unroll
          for (int r=0;r<4;r++){
            float rp = __shfl_xor(re[r], tbit);
            float ip = __shfl_xor(im[r], tbit);
            re[r] = sw ? rp : re[r];
            im[r] = sw ? ip : im[r];
          }
        }
      }

      // measure Z
      const float p0=re[0]*re[0]+im[0]*im[0];
      const float p1=re[1]*re[1]+im[1]*im[1];
      const float p2=re[2]*re[2]+im[2]*im[2];
      const float p3=re[3]*re[3]+im[3]*im[3];
      const float tot = p0+p1+p2+p3;
      float z[8];
      z[0] = (p0+p1)-(p2+p3);
      z[1] = (p0+p2)-(p1+p3);
      #pragma unroll
      for (int q=2;q<8;q++)
        z[q] = (lane & (1<<(7-q))) ? -tot : tot;
      #pragma unroll
      for (int q=0;q<8;q++){
        #pragma unroll
        for (int m=32;m;m>>=1) z[q] += __shfl_xor(z[q], m);
      }

      // H1 row m=w (bf16, swizzled): relu(z @ pW1 + pb1)
      #pragma unroll
      for (int it=0; it<HH/64; ++it){
        const int j = lane + it*64;
        float a = pb1[j];
        #pragma unroll
        for (int q=0;q<8;q++) a += z[q]*pW1[q*HH+j];
        const int col = ((((j>>3) ^ (w&7))) << 3) | (j & 7);
        H1s[w][col] = __float2bfloat16(fmaxf(a, 0.f));
      }
    }
    __syncthreads();

    // ================= Phase G: M16 GEMM (MFMA) + LSTM =================
    {
      f32x4 acc0 = (f32x4){0.f,0.f,0.f,0.f};
      f32x4 acc1 = (f32x4){0.f,0.f,0.f,0.f};
      const int m  = lane & 15;
      const int ks = lane >> 4;            // k-slot 0..3
      const __hip_bfloat16* Wb = W2p + (size_t)(w*2)*64*8;  // this wave's nf base
      #pragma unroll
      for (int kk=0; kk<16; ++kk){
        const int chunk = (kk*4 + ks) ^ (m & 7);
        bf16x8 af = *reinterpret_cast<const bf16x8*>(&H1s[m][chunk << 3]);
        // frag index = kk*32 + w*2 + fn  -> offset (kk*32+w*2+fn)*64*8 + lane*8
        const __hip_bfloat16* fb = W2p + ((size_t)(kk*32 + w*2)*64 + lane)*8;
        bf16x8 b0 = *reinterpret_cast<const bf16x8*>(fb);
        bf16x8 b1 = *reinterpret_cast<const bf16x8*>(fb + 64*8);
        acc0 = __builtin_amdgcn_mfma_f32_16x16x32_bf16(af, b0, acc0, 0,0,0);
        acc1 = __builtin_amdgcn_mfma_f32_16x16x32_bf16(af, b1, acc1, 0,0,0);
      }
      (void)Wb;

      // epilogue: acc reg r -> row (lane>>4)*4 + r = b_loc*4 + gate
      const int batch = b0 + gb;
      {
        const float bias2 = pb2[ncol0];
        const float fga = sigmoidf_(acc0[0] + bias2);
        const float iga = sigmoidf_(acc0[1] + bias2);
        const float uga = tanhf   (acc0[2] + bias2);
        const float oga = sigmoidf_(acc0[3] + bias2);
        const float c2 = fga * cx0 + iga * uga;
        const float h2 = oga * tanhf(c2);
        cx0 = c2;
        hxs[gb][ncol0] = h2;
        out[((size_t)t*BB + batch)*HH + ncol0] = h2;
        if (t == TT-1){
          out[(size_t)TT*BB*HH + (size_t)batch*HH + ncol0] = h2;
          out[(size_t)TT*BB*HH + (size_t)BB*HH + (size_t)batch*HH + ncol0] = c2;
        }
      }
      {
        const float bias2 = pb2[ncol1];
        const float fga = sigmoidf_(acc1[0] + bias2);
        const float iga = sigmoidf_(acc1[1] + bias2);
        const float uga = tanhf   (acc1[2] + bias2);
        const float oga = sigmoidf_(acc1[3] + bias2);
        const float c2 = fga * cx1 + iga * uga;
        const float h2 = oga * tanhf(c2);
        cx1 = c2;
        hxs[gb][ncol1] = h2;
        out[((size_t)t*BB + batch)*HH + ncol1] = h2;
        if (t == TT-1){
          out[(size_t)TT*BB*HH + (size_t)batch*HH + ncol1] = h2;
          out[(size_t)TT*BB*HH + (size_t)BB*HH + (size_t)batch*HH + ncol1] = c2;
        }
      }
    }
    __syncthreads();
  }
}

extern "C" void kernel_launch(void* const* d_in, const int* in_sizes, int n_in,
                              void* d_out, int out_size, void* d_ws, size_t ws_size,
                              hipStream_t stream)
{
  const float* x   = (const float*)d_in[0];
  const float* qpf = (const float*)d_in[1];
  const float* qpi = (const float*)d_in[2];
  const float* qpu = (const float*)d_in[3];
  const float* qpo = (const float*)d_in[4];
  const float* Wf  = (const float*)d_in[5];
  const float* bf  = (const float*)d_in[6];
  const float* Wi  = (const float*)d_in[7];
  const float* bi  = (const float*)d_in[8];
  const float* Wu  = (const float*)d_in[9];
  const float* bu  = (const float*)d_in[10];
  const float* Wo  = (const float*)d_in[11];
  const float* bo  = (const float*)d_in[12];
  const float* pW1 = (const float*)d_in[13];
  const float* pb1 = (const float*)d_in[14];
  const float* pW2 = (const float*)d_in[15];
  const float* pb2 = (const float*)d_in[16];

  float* out = (float*)d_out;
  __hip_bfloat16* W2p = (__hip_bfloat16*)d_ws;   // 512*512 bf16 = 512 KB

  k0_pack<<<dim3(512), dim3(64), 0, stream>>>(pW2, W2p);
  qlstm_all<<<dim3(BB/4), dim3(1024), 0, stream>>>(
      x, Wf,Wi,Wu,Wo, bf,bi,bu,bo, qpf,qpi,qpu,qpo,
      pW1, pb1, W2p, pb2, out);
}

// Round 4
// 3365.952 us; speedup vs baseline: 1.3176x; 1.3176x over previous
//
#include <hip/hip_runtime.h>
#include <hip/hip_bf16.h>
#include <math.h>

#define TT 64
#define BB 256
#define DD 512
#define HH 512
#define NBLK 256
#define LDS_BYTES 131072   // Wt[4][8][1024] f32

typedef __attribute__((ext_vector_type(8))) short bf16x8;
typedef __attribute__((ext_vector_type(4))) float f32x4;

__device__ __forceinline__ float sigmoidf_(float x){ return 1.f/(1.f+__expf(-x)); }

// ---- quantum pair helpers: amp s = lane + 64*r, r in 0..3 holds bits (7,6) ----
__device__ __forceinline__ void rx_pair(float&ra,float&ia,float&rb,float&ib,float c,float s){
  float r0=ra, i0=ia, r1=rb, i1=ib;
  ra = c*r0 + s*i1;  ia = c*i0 - s*r1;
  rb = s*i0 + c*r1;  ib = c*i1 - s*r0;
}
__device__ __forceinline__ void ry_pair(float&ra,float&ia,float&rb,float&ib,float c,float s){
  float r0=ra, i0=ia, r1=rb, i1=ib;
  ra = c*r0 - s*r1;  ia = c*i0 - s*i1;
  rb = s*r0 + c*r1;  ib = s*i0 + c*i1;
}
__device__ __forceinline__ void rz_amp(float&r,float&i,float c,float sg){
  float r0=r; r = c*r0 + sg*i; i = c*i - sg*r0;
}

// ---- one-time: pack pW2 (512x512 f32, [k][n]) into MFMA-B fragment-major bf16 ----
__global__ __launch_bounds__(64) void k0_pack(const float* __restrict__ pW2,
                                              __hip_bfloat16* __restrict__ W2p){
  const int frag = blockIdx.x;          // kk*32 + nf
  const int kk = frag >> 5, nf = frag & 31;
  const int lane = threadIdx.x;
  const int n  = nf*16 + (lane & 15);
  const int kb = kk*32 + (lane >> 4)*8;
  __hip_bfloat16 v[8];
  #pragma unroll
  for (int j=0;j<8;j++)
    v[j] = __float2bfloat16(pW2[(size_t)(kb+j)*HH + n]);
  *reinterpret_cast<uint4*>(W2p + ((size_t)frag*64 + lane)*8) =
      *reinterpret_cast<const uint4*>(v);
}

// ---- persistent kernel: 256 blocks (1/CU), 4 waves (1/SIMD), manual grid barrier ----
__global__ __launch_bounds__(256, 1) void qlstm_all(
    const float* __restrict__ x,
    const float* __restrict__ Wf, const float* __restrict__ Wi,
    const float* __restrict__ Wu, const float* __restrict__ Wo,
    const float* __restrict__ bfv, const float* __restrict__ biv,
    const float* __restrict__ buv, const float* __restrict__ bov,
    const float* __restrict__ qpf, const float* __restrict__ qpi,
    const float* __restrict__ qpu, const float* __restrict__ qpo,
    const float* __restrict__ pW1, const float* __restrict__ pb1,
    const __hip_bfloat16* __restrict__ W2p, const float* __restrict__ pb2,
    float* __restrict__ hxG, __hip_bfloat16* __restrict__ H1g,
    unsigned* __restrict__ barc, float* __restrict__ out)
{
  extern __shared__ float Wt[];         // [4][8][1024]: Wt[g*8192 + q*1024 + k]

  const int tid  = threadIdx.x;
  const int lane = tid & 63;
  const int w    = tid >> 6;            // wave 0..3 = gate in phase Q
  const int bj   = blockIdx.x;          // batch (Q) / tile id (G)

  // ---- one-time LDS fill: Wt[g][q][k] = W_g[k][q] (coalesced reads) ----
  {
    const float* Ws[4] = {Wf, Wi, Wu, Wo};
    #pragma unroll
    for (int g4=0; g4<4; ++g4){
      const float* Wg_ = Ws[g4];
      for (int idx = tid; idx < 8192; idx += 256)
        Wt[g4*8192 + (idx & 7)*1024 + (idx >> 3)] = Wg_[idx];
    }
  }

  // ---- one-time register preloads (coalesced; 1 wave/SIMD so VGPRs are free) ----
  const float* bias = (w==0)?bfv:(w==1)?biv:(w==2)?buv:bov;
  const float* qp   = (w==0)?qpf:(w==1)?qpi:(w==2)?qpu:qpo;
  const float* WtG  = Wt + w*8192;

  float biasr[8];
  #pragma unroll
  for (int q=0;q<8;q++) biasr[q] = bias[q];

  float cyq[16], syq[16], czq[16], szq[16];   // layer sincos precomputed once
  #pragma unroll
  for (int i=0;i<16;i++){
    __sincosf(0.5f*qp[i*3+0], &syq[i], &cyq[i]);
    __sincosf(0.5f*qp[i*3+1], &szq[i], &czq[i]);
  }

  float w1r[8][8], b1r[8];                    // pW1 columns this lane needs
  #pragma unroll
  for (int it=0; it<8; ++it){
    const int j = lane + it*64;
    b1r[it] = pb1[j];
    #pragma unroll
    for (int q=0;q<8;q++) w1r[it][q] = pW1[q*HH + j];
  }

  // ---- phase-G constants ----
  const int mt = bj >> 4, nt = bj & 15;
  const int mrow = mt*64 + w*16 + (lane & 15);   // A-frag row
  const int ks   = lane >> 4;                    // k-slot
  const int bt   = mt*16 + w*4 + (lane >> 4);    // epilogue batch
  const int nc0  = nt*32 + (lane & 15);
  const int nc1  = nc0 + 16;
  float cx0 = 0.f, cx1 = 0.f;
  float bias2_0, bias2_1;
  bias2_0 = pb2[nc0]; bias2_1 = pb2[nc1];

  __syncthreads();

  unsigned ibar = 0;
  auto gridbar = [&](unsigned target){
    __syncthreads();
    if (tid == 0){
      __threadfence();                         // flush my block's stores to coherence point
      atomicAdd(barc, 1u);
      while (atomicAdd(barc, 0u) < target) __builtin_amdgcn_s_sleep(1);
      __threadfence();                         // invalidate stale L1/L2 before cross-block reads
    }
    __syncthreads();
  };

  for (int t=0; t<TT; ++t){
    // ================= Phase Q: batch bj, gate w =================
    {
      float acc8[8] = {0,0,0,0,0,0,0,0};
      const float* xrow = x + ((size_t)t*BB + bj)*DD;
      #pragma unroll
      for (int it=0; it<8; ++it){
        const int k = lane + it*64;
        const float xv = xrow[k];
        #pragma unroll
        for (int q=0;q<8;q++) acc8[q] += xv * WtG[q*1024 + k];
      }
      const float* hrow = hxG + (size_t)bj*HH;
      #pragma unroll
      for (int it=0; it<8; ++it){
        const int k = lane + it*64;
        const float hv = hrow[k];
        #pragma unroll
        for (int q=0;q<8;q++) acc8[q] += hv * WtG[q*1024 + 512 + k];
      }
      float th[8];
      #pragma unroll
      for (int q=0;q<8;q++){
        #pragma unroll
        for (int m=32;m;m>>=1) acc8[q] += __shfl_xor(acc8[q], m);
        th[q] = acc8[q] + biasr[q];
      }

      // statevector: 256 amps, lane holds s = lane + 64*r
      float re[4]={0.f,0.f,0.f,0.f}, im[4]={0.f,0.f,0.f,0.f};
      if (lane==0) re[0]=1.f;

      #pragma unroll
      for (int q=0;q<8;q++){
        float s,c; __sincosf(0.5f*th[q], &s, &c);
        if (q==0){
          rx_pair(re[0],im[0],re[2],im[2],c,s);
          rx_pair(re[1],im[1],re[3],im[3],c,s);
        } else if (q==1){
          rx_pair(re[0],im[0],re[1],im[1],c,s);
          rx_pair(re[2],im[2],re[3],im[3],c,s);
        } else {
          const int mask = 1<<(7-q);
          #pragma unroll
          for (int r=0;r<4;r++){
            float rp = __shfl_xor(re[r], mask);
            float ip = __shfl_xor(im[r], mask);
            re[r] = c*re[r] + s*ip;
            im[r] = c*im[r] - s*rp;
          }
        }
      }

      #pragma unroll
      for (int l=0;l<2;l++){
        #pragma unroll
        for (int q=0;q<8;q++){
          const float cy = cyq[l*8+q], sy = syq[l*8+q];
          if (q==0){
            ry_pair(re[0],im[0],re[2],im[2],cy,sy);
            ry_pair(re[1],im[1],re[3],im[3],cy,sy);
          } else if (q==1){
            ry_pair(re[0],im[0],re[1],im[1],cy,sy);
            ry_pair(re[2],im[2],re[3],im[3],cy,sy);
          } else {
            const int mask = 1<<(7-q);
            const float sg = (lane & mask) ? sy : -sy;
            #pragma unroll
            for (int r=0;r<4;r++){
              float rp = __shfl_xor(re[r], mask);
              float ip = __shfl_xor(im[r], mask);
              re[r] = cy*re[r] + sg*rp;
              im[r] = cy*im[r] + sg*ip;
            }
          }
          const float cz = czq[l*8+q], sz = szq[l*8+q];
          if (q==0){
            rz_amp(re[0],im[0],cz, sz); rz_amp(re[1],im[1],cz, sz);
            rz_amp(re[2],im[2],cz,-sz); rz_amp(re[3],im[3],cz,-sz);
          } else if (q==1){
            rz_amp(re[0],im[0],cz, sz); rz_amp(re[2],im[2],cz, sz);
            rz_amp(re[1],im[1],cz,-sz); rz_amp(re[3],im[3],cz,-sz);
          } else {
            const int mask = 1<<(7-q);
            const float sg = (lane & mask) ? -sz : sz;
            #pragma unroll
            for (int r=0;r<4;r++) rz_amp(re[r],im[r],cz,sg);
          }
        }
        { float tr=re[2]; re[2]=re[3]; re[3]=tr;
          float ti=im[2]; im[2]=im[3]; im[3]=ti; }
        re[1]=__shfl_xor(re[1],32); im[1]=__shfl_xor(im[1],32);
        re[3]=__shfl_xor(re[3],32); im[3]=__shfl_xor(im[3],32);
        #pragma unroll
        for (int cq=2;cq<7;cq++){
          const int cbit = 1<<(7-cq), tbit = 1<<(6-cq);
          const bool sw = (lane & cbit) != 0;
          #pragma unroll
          for (int r=0;r<4;r++){
            float rp = __shfl_xor(re[r], tbit);
            float ip = __shfl_xor(im[r], tbit);
            re[r] = sw ? rp : re[r];
            im[r] = sw ? ip : im[r];
          }
        }
      }

      // measure Z
      const float p0=re[0]*re[0]+im[0]*im[0];
      const float p1=re[1]*re[1]+im[1]*im[1];
      const float p2=re[2]*re[2]+im[2]*im[2];
      const float p3=re[3]*re[3]+im[3]*im[3];
      const float tot = p0+p1+p2+p3;
      float z[8];
      z[0] = (p0+p1)-(p2+p3);
      z[1] = (p0+p2)-(p1+p3);
      #pragma unroll
      for (int q=2;q<8;q++)
        z[q] = (lane & (1<<(7-q))) ? -tot : tot;
      #pragma unroll
      for (int q=0;q<8;q++){
        #pragma unroll
        for (int m=32;m;m>>=1) z[q] += __shfl_xor(z[q], m);
      }

      // H1 row (bf16, row-major): relu(z @ pW1 + pb1) — all-register weights
      __hip_bfloat16* h1row = H1g + ((size_t)bj*4 + w)*HH;
      #pragma unroll
      for (int it=0; it<8; ++it){
        const int j = lane + it*64;
        float a = b1r[it];
        #pragma unroll
        for (int q=0;q<8;q++) a += z[q]*w1r[it][q];
        h1row[j] = __float2bfloat16(fmaxf(a, 0.f));
      }
    }
    ibar += 1; gridbar(ibar*NBLK);

    // ================= Phase G: tile (mt,nt), 64x32, K=512 =================
    {
      f32x4 a0 = (f32x4){0.f,0.f,0.f,0.f};
      f32x4 a1 = (f32x4){0.f,0.f,0.f,0.f};
      #pragma unroll
      for (int kk=0; kk<16; ++kk){
        bf16x8 af = *reinterpret_cast<const bf16x8*>(H1g + (size_t)mrow*HH + kk*32 + ks*8);
        const __hip_bfloat16* fb = W2p + ((size_t)(kk*32 + nt*2)*64 + lane)*8;
        bf16x8 b0 = *reinterpret_cast<const bf16x8*>(fb);
        bf16x8 b1 = *reinterpret_cast<const bf16x8*>(fb + 512);
        a0 = __builtin_amdgcn_mfma_f32_16x16x32_bf16(af, b0, a0, 0,0,0);
        a1 = __builtin_amdgcn_mfma_f32_16x16x32_bf16(af, b1, a1, 0,0,0);
      }
      {
        const float fga = sigmoidf_(a0[0] + bias2_0);
        const float iga = sigmoidf_(a0[1] + bias2_0);
        const float uga = tanhf   (a0[2] + bias2_0);
        const float oga = sigmoidf_(a0[3] + bias2_0);
        const float c2 = fga*cx0 + iga*uga;
        const float h2 = oga * tanhf(c2);
        cx0 = c2;
        hxG[(size_t)bt*HH + nc0] = h2;
        out[((size_t)t*BB + bt)*HH + nc0] = h2;
        if (t == TT-1){
          out[(size_t)TT*BB*HH + (size_t)bt*HH + nc0] = h2;
          out[(size_t)TT*BB*HH + (size_t)BB*HH + (size_t)bt*HH + nc0] = c2;
        }
      }
      {
        const float fga = sigmoidf_(a1[0] + bias2_1);
        const float iga = sigmoidf_(a1[1] + bias2_1);
        const float uga = tanhf   (a1[2] + bias2_1);
        const float oga = sigmoidf_(a1[3] + bias2_1);
        const float c2 = fga*cx1 + iga*uga;
        const float h2 = oga * tanhf(c2);
        cx1 = c2;
        hxG[(size_t)bt*HH + nc1] = h2;
        out[((size_t)t*BB + bt)*HH + nc1] = h2;
        if (t == TT-1){
          out[(size_t)TT*BB*HH + (size_t)bt*HH + nc1] = h2;
          out[(size_t)TT*BB*HH + (size_t)BB*HH + (size_t)bt*HH + nc1] = c2;
        }
      }
    }
    if (t != TT-1){ ibar += 1; gridbar(ibar*NBLK); }
  }
}

extern "C" void kernel_launch(void* const* d_in, const int* in_sizes, int n_in,
                              void* d_out, int out_size, void* d_ws, size_t ws_size,
                              hipStream_t stream)
{
  const float* x   = (const float*)d_in[0];
  const float* qpf = (const float*)d_in[1];
  const float* qpi = (const float*)d_in[2];
  const float* qpu = (const float*)d_in[3];
  const float* qpo = (const float*)d_in[4];
  const float* Wf  = (const float*)d_in[5];
  const float* bf  = (const float*)d_in[6];
  const float* Wi  = (const float*)d_in[7];
  const float* bi  = (const float*)d_in[8];
  const float* Wu  = (const float*)d_in[9];
  const float* bu  = (const float*)d_in[10];
  const float* Wo  = (const float*)d_in[11];
  const float* bo  = (const float*)d_in[12];
  const float* pW1 = (const float*)d_in[13];
  const float* pb1 = (const float*)d_in[14];
  const float* pW2 = (const float*)d_in[15];
  const float* pb2 = (const float*)d_in[16];

  float* out = (float*)d_out;
  unsigned* barc      = (unsigned*)d_ws;                                        // 256 B
  float*    hxG       = (float*)((char*)d_ws + 256);                            // 512 KB
  __hip_bfloat16* W2p = (__hip_bfloat16*)((char*)d_ws + 256 + 524288);          // 512 KB
  __hip_bfloat16* H1g = (__hip_bfloat16*)((char*)d_ws + 256 + 524288 + 524288); // 1 MB

  // allow >64KB dynamic LDS (no-op/harmless if not required on ROCm)
  (void)hipFuncSetAttribute((const void*)qlstm_all,
                            hipFuncAttributeMaxDynamicSharedMemorySize, LDS_BYTES);

  hipMemsetAsync(d_ws, 0, 256 + 524288, stream);   // barrier counter + hx=0
  k0_pack<<<dim3(512), dim3(64), 0, stream>>>(pW2, W2p);
  qlstm_all<<<dim3(NBLK), dim3(256), LDS_BYTES, stream>>>(
      x, Wf,Wi,Wu,Wo, bf,bi,bu,bo, qpf,qpi,qpu,qpo,
      pW1,pb1, W2p, pb2, hxG, H1g, barc, out);
}

// Round 5
// 3330.852 us; speedup vs baseline: 1.3315x; 1.0105x over previous
//
#include <hip/hip_runtime.h>
#include <hip/hip_bf16.h>
#include <math.h>

#define TT 64
#define BB 256
#define DD 512
#define HH 512
#define NBLK 128
#define LDS_BYTES 143360   // Wt 128KB + H1s 8KB + hxs 4KB

typedef __attribute__((ext_vector_type(8))) short bf16x8;
typedef __attribute__((ext_vector_type(4))) float f32x4;

__device__ __forceinline__ float sigmoidf_(float x){ return 1.f/(1.f+__expf(-x)); }

// ---- quantum pair helpers: amp s = lane + 64*r, r in 0..3 holds bits (7,6) ----
__device__ __forceinline__ void rx_pair(float&ra,float&ia,float&rb,float&ib,float c,float s){
  float r0=ra, i0=ia, r1=rb, i1=ib;
  ra = c*r0 + s*i1;  ia = c*i0 - s*r1;
  rb = s*i0 + c*r1;  ib = c*i1 - s*r0;
}
__device__ __forceinline__ void ry_pair(float&ra,float&ia,float&rb,float&ib,float c,float s){
  float r0=ra, i0=ia, r1=rb, i1=ib;
  ra = c*r0 - s*r1;  ia = c*i0 - s*i1;
  rb = s*r0 + c*r1;  ib = s*i0 + c*i1;
}
__device__ __forceinline__ void rz_amp(float&r,float&i,float c,float sg){
  float r0=r; r = c*r0 + sg*i; i = c*i - sg*r0;
}

// ---- one-time: pack pW2 (512x512 f32, [k][n]) into MFMA-B fragment-major bf16 ----
__global__ __launch_bounds__(64) void k0_pack(const float* __restrict__ pW2,
                                              __hip_bfloat16* __restrict__ W2p){
  const int frag = blockIdx.x;          // kk*32 + nf
  const int kk = frag >> 5, nf = frag & 31;
  const int lane = threadIdx.x;
  const int n  = nf*16 + (lane & 15);
  const int kb = kk*32 + (lane >> 4)*8;
  __hip_bfloat16 v[8];
  #pragma unroll
  for (int j=0;j<8;j++)
    v[j] = __float2bfloat16(pW2[(size_t)(kb+j)*HH + n]);
  *reinterpret_cast<uint4*>(W2p + ((size_t)frag*64 + lane)*8) =
      *reinterpret_cast<const uint4*>(v);
}

// ---- zero-barrier persistent kernel: block = 2 batches end-to-end, 8 waves ----
__global__ __launch_bounds__(512, 2) void qlstm_all(
    const float* __restrict__ x,
    const float* __restrict__ Wf, const float* __restrict__ Wi,
    const float* __restrict__ Wu, const float* __restrict__ Wo,
    const float* __restrict__ bfv, const float* __restrict__ biv,
    const float* __restrict__ buv, const float* __restrict__ bov,
    const float* __restrict__ qpf, const float* __restrict__ qpi,
    const float* __restrict__ qpu, const float* __restrict__ qpo,
    const float* __restrict__ pW1, const float* __restrict__ pb1,
    const __hip_bfloat16* __restrict__ W2p, const float* __restrict__ pb2,
    float* __restrict__ out)
{
  extern __shared__ char smem[];
  float* Wt = (float*)smem;                                    // [4][8][1024]
  __hip_bfloat16* H1s = (__hip_bfloat16*)(smem + 131072);      // [8][512] swizzled
  float* hxs = (float*)(smem + 131072 + 8192);                 // [2][512]

  const int tid  = threadIdx.x;
  const int lane = tid & 63;
  const int w    = tid >> 6;            // wave 0..7
  const int B0   = blockIdx.x * 2;

  // phase-Q roles: wave w -> (batch-local bq, gate g), row m = bq*4+g = w
  const int bq = w >> 2;
  const int g  = w & 3;

  // ---- one-time LDS fill: Wt[g][q][k] = W_g[k][q] ----
  {
    const float* Ws[4] = {Wf, Wi, Wu, Wo};
    #pragma unroll
    for (int g4=0; g4<4; ++g4){
      const float* Wg_ = Ws[g4];
      for (int idx = tid; idx < 8192; idx += 512)
        Wt[g4*8192 + (idx & 7)*1024 + (idx >> 3)] = Wg_[idx];
    }
    for (int i = tid; i < 1024; i += 512) hxs[i] = 0.f;
  }

  // ---- one-time register preloads ----
  const float* bias = (g==0)?bfv:(g==1)?biv:(g==2)?buv:bov;
  const float* qp   = (g==0)?qpf:(g==1)?qpi:(g==2)?qpu:qpo;
  const float* WtG  = Wt + g*8192;

  float biasr[8];
  #pragma unroll
  for (int q=0;q<8;q++) biasr[q] = bias[q];

  float cyq[16], syq[16], czq[16], szq[16];
  #pragma unroll
  for (int i=0;i<16;i++){
    __sincosf(0.5f*qp[i*3+0], &syq[i], &cyq[i]);
    __sincosf(0.5f*qp[i*3+1], &szq[i], &czq[i]);
  }

  float w1r[8][8], b1r[8];
  #pragma unroll
  for (int it=0; it<8; ++it){
    const int j = lane + it*64;
    b1r[it] = pb1[j];
    #pragma unroll
    for (int q=0;q<8;q++) w1r[it][q] = pW1[q*HH + j];
  }

  // ---- phase-G per-thread state: wave owns N-slice [w*64, w*64+64) ----
  float bias2r[4];
  #pragma unroll
  for (int nf=0; nf<4; ++nf) bias2r[nf] = pb2[w*64 + nf*16 + (lane & 15)];
  float cxr[4] = {0.f, 0.f, 0.f, 0.f};

  __syncthreads();

  for (int t=0; t<TT; ++t){
    // ================= Phase Q: batch B0+bq, gate g =================
    {
      float acc8[8] = {0,0,0,0,0,0,0,0};
      const float* xrow = x + ((size_t)t*BB + B0 + bq)*DD;
      #pragma unroll
      for (int it=0; it<8; ++it){
        const int k = lane + it*64;
        const float xv = xrow[k];
        #pragma unroll
        for (int q=0;q<8;q++) acc8[q] += xv * WtG[q*1024 + k];
      }
      const float* hrow = hxs + bq*512;
      #pragma unroll
      for (int it=0; it<8; ++it){
        const int k = lane + it*64;
        const float hv = hrow[k];
        #pragma unroll
        for (int q=0;q<8;q++) acc8[q] += hv * WtG[q*1024 + 512 + k];
      }
      float th[8];
      #pragma unroll
      for (int q=0;q<8;q++){
        #pragma unroll
        for (int m=32;m;m>>=1) acc8[q] += __shfl_xor(acc8[q], m);
        th[q] = acc8[q] + biasr[q];
      }

      // statevector: 256 amps, lane holds s = lane + 64*r
      float re[4]={0.f,0.f,0.f,0.f}, im[4]={0.f,0.f,0.f,0.f};
      if (lane==0) re[0]=1.f;

      #pragma unroll
      for (int q=0;q<8;q++){
        float s,c; __sincosf(0.5f*th[q], &s, &c);
        if (q==0){
          rx_pair(re[0],im[0],re[2],im[2],c,s);
          rx_pair(re[1],im[1],re[3],im[3],c,s);
        } else if (q==1){
          rx_pair(re[0],im[0],re[1],im[1],c,s);
          rx_pair(re[2],im[2],re[3],im[3],c,s);
        } else {
          const int mask = 1<<(7-q);
          #pragma unroll
          for (int r=0;r<4;r++){
            float rp = __shfl_xor(re[r], mask);
            float ip = __shfl_xor(im[r], mask);
            re[r] = c*re[r] + s*ip;
            im[r] = c*im[r] - s*rp;
          }
        }
      }

      #pragma unroll
      for (int l=0;l<2;l++){
        #pragma unroll
        for (int q=0;q<8;q++){
          const float cy = cyq[l*8+q], sy = syq[l*8+q];
          if (q==0){
            ry_pair(re[0],im[0],re[2],im[2],cy,sy);
            ry_pair(re[1],im[1],re[3],im[3],cy,sy);
          } else if (q==1){
            ry_pair(re[0],im[0],re[1],im[1],cy,sy);
            ry_pair(re[2],im[2],re[3],im[3],cy,sy);
          } else {
            const int mask = 1<<(7-q);
            const float sg = (lane & mask) ? sy : -sy;
            #pragma unroll
            for (int r=0;r<4;r++){
              float rp = __shfl_xor(re[r], mask);
              float ip = __shfl_xor(im[r], mask);
              re[r] = cy*re[r] + sg*rp;
              im[r] = cy*im[r] + sg*ip;
            }
          }
          const float cz = czq[l*8+q], sz = szq[l*8+q];
          if (q==0){
            rz_amp(re[0],im[0],cz, sz); rz_amp(re[1],im[1],cz, sz);
            rz_amp(re[2],im[2],cz,-sz); rz_amp(re[3],im[3],cz,-sz);
          } else if (q==1){
            rz_amp(re[0],im[0],cz, sz); rz_amp(re[2],im[2],cz, sz);
            rz_amp(re[1],im[1],cz,-sz); rz_amp(re[3],im[3],cz,-sz);
          } else {
            const int mask = 1<<(7-q);
            const float sg = (lane & mask) ? -sz : sz;
            #pragma unroll
            for (int r=0;r<4;r++) rz_amp(re[r],im[r],cz,sg);
          }
        }
        { float tr=re[2]; re[2]=re[3]; re[3]=tr;
          float ti=im[2]; im[2]=im[3]; im[3]=ti; }
        re[1]=__shfl_xor(re[1],32); im[1]=__shfl_xor(im[1],32);
        re[3]=__shfl_xor(re[3],32); im[3]=__shfl_xor(im[3],32);
        #pragma unroll
        for (int cq=2;cq<7;cq++){
          const int cbit = 1<<(7-cq), tbit = 1<<(6-cq);
          const bool sw = (lane & cbit) != 0;
          #pragma unroll
          for (int r=0;r<4;r++){
            float rp = __shfl_xor(re[r], tbit);
            float ip = __shfl_xor(im[r], tbit);
            re[r] = sw ? rp : re[r];
            im[r] = sw ? ip : im[r];
          }
        }
      }

      // measure Z
      const float p0=re[0]*re[0]+im[0]*im[0];
      const float p1=re[1]*re[1]+im[1]*im[1];
      const float p2=re[2]*re[2]+im[2]*im[2];
      const float p3=re[3]*re[3]+im[3]*im[3];
      const float tot = p0+p1+p2+p3;
      float z[8];
      z[0] = (p0+p1)-(p2+p3);
      z[1] = (p0+p2)-(p1+p3);
      #pragma unroll
      for (int q=2;q<8;q++)
        z[q] = (lane & (1<<(7-q))) ? -tot : tot;
      #pragma unroll
      for (int q=0;q<8;q++){
        #pragma unroll
        for (int m=32;m;m>>=1) z[q] += __shfl_xor(z[q], m);
      }

      // H1 row m=w (bf16, 16B-chunk XOR swizzle by row): relu(z @ pW1 + pb1)
      #pragma unroll
      for (int it=0; it<8; ++it){
        const int j = lane + it*64;
        float a = b1r[it];
        #pragma unroll
        for (int q=0;q<8;q++) a += z[q]*w1r[it][q];
        const int col = (((j>>3) ^ w) << 3) | (j & 7);
        H1s[w*512 + col] = __float2bfloat16(fmaxf(a, 0.f));
      }
    }
    __syncthreads();

    // ================= Phase G: wave w -> N-slice [w*64, w*64+64) =================
    {
      f32x4 ac[4];
      #pragma unroll
      for (int nf=0; nf<4; ++nf) ac[nf] = (f32x4){0.f,0.f,0.f,0.f};
      const int arow = lane & 7;     // rows 8..15 duplicate 0..7 (outputs unused)
      const int ks   = lane >> 4;
      #pragma unroll
      for (int kk=0; kk<16; ++kk){
        const int chunk = (kk*4 + ks) ^ arow;
        bf16x8 af = *reinterpret_cast<const bf16x8*>(&H1s[arow*512 + (chunk<<3)]);
        const __hip_bfloat16* fb = W2p + ((size_t)(kk*32 + w*4)*64 + lane)*8;
        #pragma unroll
        for (int nf=0; nf<4; ++nf)
          ac[nf] = __builtin_amdgcn_mfma_f32_16x16x32_bf16(
              af, *reinterpret_cast<const bf16x8*>(fb + nf*512), ac[nf], 0,0,0);
      }

      // epilogue: C row (lane>>4)*4 + r = bq*4 + gate; lanes 32..63 are duplicates
      if (lane < 32){
        const int a4 = lane >> 4;            // batch-local
        const int batch = B0 + a4;
        #pragma unroll
        for (int nf=0; nf<4; ++nf){
          const int n = w*64 + nf*16 + (lane & 15);
          const float fga = sigmoidf_(ac[nf][0] + bias2r[nf]);
          const float iga = sigmoidf_(ac[nf][1] + bias2r[nf]);
          const float uga = tanhf   (ac[nf][2] + bias2r[nf]);
          const float oga = sigmoidf_(ac[nf][3] + bias2r[nf]);
          const float c2 = fga*cxr[nf] + iga*uga;
          const float h2 = oga * tanhf(c2);
          cxr[nf] = c2;
          hxs[a4*512 + n] = h2;
          out[((size_t)t*BB + batch)*HH + n] = h2;
          if (t == TT-1){
            out[(size_t)TT*BB*HH + (size_t)batch*HH + n] = h2;
            out[(size_t)TT*BB*HH + (size_t)BB*HH + (size_t)batch*HH + n] = c2;
          }
        }
      }
    }
    __syncthreads();
  }
}

extern "C" void kernel_launch(void* const* d_in, const int* in_sizes, int n_in,
                              void* d_out, int out_size, void* d_ws, size_t ws_size,
                              hipStream_t stream)
{
  const float* x   = (const float*)d_in[0];
  const float* qpf = (const float*)d_in[1];
  const float* qpi = (const float*)d_in[2];
  const float* qpu = (const float*)d_in[3];
  const float* qpo = (const float*)d_in[4];
  const float* Wf  = (const float*)d_in[5];
  const float* bf  = (const float*)d_in[6];
  const float* Wi  = (const float*)d_in[7];
  const float* bi  = (const float*)d_in[8];
  const float* Wu  = (const float*)d_in[9];
  const float* bu  = (const float*)d_in[10];
  const float* Wo  = (const float*)d_in[11];
  const float* bo  = (const float*)d_in[12];
  const float* pW1 = (const float*)d_in[13];
  const float* pb1 = (const float*)d_in[14];
  const float* pW2 = (const float*)d_in[15];
  const float* pb2 = (const float*)d_in[16];

  float* out = (float*)d_out;
  __hip_bfloat16* W2p = (__hip_bfloat16*)d_ws;   // 512 KB

  (void)hipFuncSetAttribute((const void*)qlstm_all,
                            hipFuncAttributeMaxDynamicSharedMemorySize, LDS_BYTES);

  k0_pack<<<dim3(512), dim3(64), 0, stream>>>(pW2, W2p);
  qlstm_all<<<dim3(NBLK), dim3(512), LDS_BYTES, stream>>>(
      x, Wf,Wi,Wu,Wo, bf,bi,bu,bo, qpf,qpi,qpu,qpo,
      pW1,pb1, W2p, pb2, out);
}

// Round 6
// 3137.312 us; speedup vs baseline: 1.4137x; 1.0617x over previous
//
#include <hip/hip_runtime.h>
#include <hip/hip_bf16.h>
#include <math.h>

#define TT 64
#define BB 256
#define DD 512
#define HH 512
#define NBLK 128
#define LDS_BYTES 143360   // Wt 128KB + H1s 8KB + hxs 4KB

typedef __attribute__((ext_vector_type(8))) short bf16x8;
typedef __attribute__((ext_vector_type(4))) float f32x4;

__device__ __forceinline__ float sigmoidf_(float x){ return 1.f/(1.f+__expf(-x)); }

// ---- quantum pair helpers: amp s = lane + 64*r, r in 0..3 holds bits (7,6) ----
__device__ __forceinline__ void rx_pair(float&ra,float&ia,float&rb,float&ib,float c,float s){
  float r0=ra, i0=ia, r1=rb, i1=ib;
  ra = c*r0 + s*i1;  ia = c*i0 - s*r1;
  rb = s*i0 + c*r1;  ib = c*i1 - s*r0;
}
__device__ __forceinline__ void ry_pair(float&ra,float&ia,float&rb,float&ib,float c,float s){
  float r0=ra, i0=ia, r1=rb, i1=ib;
  ra = c*r0 - s*r1;  ia = c*i0 - s*i1;
  rb = s*r0 + c*r1;  ib = s*i0 + c*i1;
}
__device__ __forceinline__ void rz_amp(float&r,float&i,float c,float sg){
  float r0=r; r = c*r0 + sg*i; i = c*i - sg*r0;
}

// ---- one-time: pack pW2 (512x512 f32, [k][n]) into MFMA-B fragment-major bf16 ----
__global__ __launch_bounds__(64) void k0_pack(const float* __restrict__ pW2,
                                              __hip_bfloat16* __restrict__ W2p){
  const int frag = blockIdx.x;          // kk*32 + nf
  const int kk = frag >> 5, nf = frag & 31;
  const int lane = threadIdx.x;
  const int n  = nf*16 + (lane & 15);
  const int kb = kk*32 + (lane >> 4)*8;
  __hip_bfloat16 v[8];
  #pragma unroll
  for (int j=0;j<8;j++)
    v[j] = __float2bfloat16(pW2[(size_t)(kb+j)*HH + n]);
  *reinterpret_cast<uint4*>(W2p + ((size_t)frag*64 + lane)*8) =
      *reinterpret_cast<const uint4*>(v);
}

// ---- zero-dependency persistent kernel: block = 2 batches end-to-end, 8 waves ----
__global__ __launch_bounds__(512, 2) void qlstm_all(
    const float* __restrict__ x,
    const float* __restrict__ Wf, const float* __restrict__ Wi,
    const float* __restrict__ Wu, const float* __restrict__ Wo,
    const float* __restrict__ bfv, const float* __restrict__ biv,
    const float* __restrict__ buv, const float* __restrict__ bov,
    const float* __restrict__ qpf, const float* __restrict__ qpi,
    const float* __restrict__ qpu, const float* __restrict__ qpo,
    const float* __restrict__ pW1, const float* __restrict__ pb1,
    const __hip_bfloat16* __restrict__ W2p, const float* __restrict__ pb2,
    unsigned* __restrict__ pace, float* __restrict__ out)
{
  extern __shared__ char smem[];
  float* Wt = (float*)smem;                                    // [4][8][1024]
  __hip_bfloat16* H1s = (__hip_bfloat16*)(smem + 131072);      // [8][512] swizzled
  float* hxs = (float*)(smem + 131072 + 8192);                 // [2][512]

  const int tid  = threadIdx.x;
  const int lane = tid & 63;
  const int w    = tid >> 6;            // wave 0..7
  const int B0   = blockIdx.x * 2;
  const int pgrp = (blockIdx.x & 7) * 32;   // pacing group counter (128B apart)

  // phase-Q roles: wave w -> (batch-local bq, gate g), row m = bq*4+g = w
  const int bq = w >> 2;
  const int g  = w & 3;

  // ---- one-time LDS fill: Wt[g][q][k] = W_g[k][q] ----
  {
    const float* Ws[4] = {Wf, Wi, Wu, Wo};
    #pragma unroll
    for (int g4=0; g4<4; ++g4){
      const float* Wg_ = Ws[g4];
      for (int idx = tid; idx < 8192; idx += 512)
        Wt[g4*8192 + (idx & 7)*1024 + (idx >> 3)] = Wg_[idx];
    }
    for (int i = tid; i < 1024; i += 512) hxs[i] = 0.f;
  }

  // ---- one-time register preloads ----
  const float* bias = (g==0)?bfv:(g==1)?biv:(g==2)?buv:bov;
  const float* qp   = (g==0)?qpf:(g==1)?qpi:(g==2)?qpu:qpo;
  const float* WtG  = Wt + g*8192;

  float biasr[8];
  #pragma unroll
  for (int q=0;q<8;q++) biasr[q] = bias[q];

  float cyq[16], syq[16], czq[16], szq[16];
  #pragma unroll
  for (int i=0;i<16;i++){
    __sincosf(0.5f*qp[i*3+0], &syq[i], &cyq[i]);
    __sincosf(0.5f*qp[i*3+1], &szq[i], &czq[i]);
  }

  float w1r[8][8], b1r[8];
  #pragma unroll
  for (int it=0; it<8; ++it){
    const int j = lane + it*64;
    b1r[it] = pb1[j];
    #pragma unroll
    for (int q=0;q<8;q++) w1r[it][q] = pW1[q*HH + j];
  }

  // ---- phase-G per-thread state: wave owns N-slice [w*64, w*64+64) ----
  float bias2r[4];
  #pragma unroll
  for (int nf=0; nf<4; ++nf) bias2r[nf] = pb2[w*64 + nf*16 + (lane & 15)];
  float cxr[4] = {0.f, 0.f, 0.f, 0.f};

  __syncthreads();

  for (int t=0; t<TT; ++t){
    // ================= Phase Q: batch B0+bq, gate g =================
    {
      float acc8[8] = {0,0,0,0,0,0,0,0};
      const float* xrow = x + ((size_t)t*BB + B0 + bq)*DD;
      #pragma unroll
      for (int it=0; it<8; ++it){
        const int k = lane + it*64;
        const float xv = xrow[k];
        #pragma unroll
        for (int q=0;q<8;q++) acc8[q] += xv * WtG[q*1024 + k];
      }
      const float* hrow = hxs + bq*512;
      #pragma unroll
      for (int it=0; it<8; ++it){
        const int k = lane + it*64;
        const float hv = hrow[k];
        #pragma unroll
        for (int q=0;q<8;q++) acc8[q] += hv * WtG[q*1024 + 512 + k];
      }
      float th[8];
      #pragma unroll
      for (int q=0;q<8;q++){
        #pragma unroll
        for (int m=32;m;m>>=1) acc8[q] += __shfl_xor(acc8[q], m);
        th[q] = acc8[q] + biasr[q];
      }

      // statevector: 256 amps, lane holds s = lane + 64*r
      float re[4]={0.f,0.f,0.f,0.f}, im[4]={0.f,0.f,0.f,0.f};
      if (lane==0) re[0]=1.f;

      #pragma unroll
      for (int q=0;q<8;q++){
        float s,c; __sincosf(0.5f*th[q], &s, &c);
        if (q==0){
          rx_pair(re[0],im[0],re[2],im[2],c,s);
          rx_pair(re[1],im[1],re[3],im[3],c,s);
        } else if (q==1){
          rx_pair(re[0],im[0],re[1],im[1],c,s);
          rx_pair(re[2],im[2],re[3],im[3],c,s);
        } else {
          const int mask = 1<<(7-q);
          #pragma unroll
          for (int r=0;r<4;r++){
            float rp = __shfl_xor(re[r], mask);
            float ip = __shfl_xor(im[r], mask);
            re[r] = c*re[r] + s*ip;
            im[r] = c*im[r] - s*rp;
          }
        }
      }

      #pragma unroll
      for (int l=0;l<2;l++){
        #pragma unroll
        for (int q=0;q<8;q++){
          const float cy = cyq[l*8+q], sy = syq[l*8+q];
          if (q==0){
            ry_pair(re[0],im[0],re[2],im[2],cy,sy);
            ry_pair(re[1],im[1],re[3],im[3],cy,sy);
          } else if (q==1){
            ry_pair(re[0],im[0],re[1],im[1],cy,sy);
            ry_pair(re[2],im[2],re[3],im[3],cy,sy);
          } else {
            const int mask = 1<<(7-q);
            const float sg = (lane & mask) ? sy : -sy;
            #pragma unroll
            for (int r=0;r<4;r++){
              float rp = __shfl_xor(re[r], mask);
              float ip = __shfl_xor(im[r], mask);
              re[r] = cy*re[r] + sg*rp;
              im[r] = cy*im[r] + sg*ip;
            }
          }
          const float cz = czq[l*8+q], sz = szq[l*8+q];
          if (q==0){
            rz_amp(re[0],im[0],cz, sz); rz_amp(re[1],im[1],cz, sz);
            rz_amp(re[2],im[2],cz,-sz); rz_amp(re[3],im[3],cz,-sz);
          } else if (q==1){
            rz_amp(re[0],im[0],cz, sz); rz_amp(re[2],im[2],cz, sz);
            rz_amp(re[1],im[1],cz,-sz); rz_amp(re[3],im[3],cz,-sz);
          } else {
            const int mask = 1<<(7-q);
            const float sg = (lane & mask) ? -sz : sz;
            #pragma unroll
            for (int r=0;r<4;r++) rz_amp(re[r],im[r],cz,sg);
          }
        }
        { float tr=re[2]; re[2]=re[3]; re[3]=tr;
          float ti=im[2]; im[2]=im[3]; im[3]=ti; }
        re[1]=__shfl_xor(re[1],32); im[1]=__shfl_xor(im[1],32);
        re[3]=__shfl_xor(re[3],32); im[3]=__shfl_xor(im[3],32);
        #pragma unroll
        for (int cq=2;cq<7;cq++){
          const int cbit = 1<<(7-cq), tbit = 1<<(6-cq);
          const bool sw = (lane & cbit) != 0;
          #pragma unroll
          for (int r=0;r<4;r++){
            float rp = __shfl_xor(re[r], tbit);
            float ip = __shfl_xor(im[r], tbit);
            re[r] = sw ? rp : re[r];
            im[r] = sw ? ip : im[r];
          }
        }
      }

      // measure Z
      const float p0=re[0]*re[0]+im[0]*im[0];
      const float p1=re[1]*re[1]+im[1]*im[1];
      const float p2=re[2]*re[2]+im[2]*im[2];
      const float p3=re[3]*re[3]+im[3]*im[3];
      const float tot = p0+p1+p2+p3;
      float z[8];
      z[0] = (p0+p1)-(p2+p3);
      z[1] = (p0+p2)-(p1+p3);
      #pragma unroll
      for (int q=2;q<8;q++)
        z[q] = (lane & (1<<(7-q))) ? -tot : tot;
      #pragma unroll
      for (int q=0;q<8;q++){
        #pragma unroll
        for (int m=32;m;m>>=1) z[q] += __shfl_xor(z[q], m);
      }

      // H1 row m=w (bf16, 16B-chunk XOR swizzle by row): relu(z @ pW1 + pb1)
      #pragma unroll
      for (int it=0; it<8; ++it){
        const int j = lane + it*64;
        float a = b1r[it];
        #pragma unroll
        for (int q=0;q<8;q++) a += z[q]*w1r[it][q];
        const int col = (((j>>3) ^ w) << 3) | (j & 7);
        H1s[w*512 + col] = __float2bfloat16(fmaxf(a, 0.f));
      }
    }

    // ---- advisory pacing barrier (locality only; bounded, fence-free) ----
    if (tid == 0){
      const unsigned tgt = 16u*(unsigned)(t+1);
      atomicAdd(&pace[pgrp], 1u);
      int spins = 0;
      while (__hip_atomic_load(&pace[pgrp], __ATOMIC_RELAXED,
                               __HIP_MEMORY_SCOPE_AGENT) < tgt && ++spins < 768)
        __builtin_amdgcn_s_sleep(2);
    }
    __syncthreads();

    // ================= Phase G: wave w -> N-slice [w*64, w*64+64) =================
    {
      f32x4 ac[4];
      #pragma unroll
      for (int nf=0; nf<4; ++nf) ac[nf] = (f32x4){0.f,0.f,0.f,0.f};
      const int arow = lane & 7;     // rows 8..15 duplicate 0..7 (outputs unused)
      const int ks   = lane >> 4;
      #pragma unroll
      for (int kk=0; kk<16; ++kk){
        const int chunk = (kk*4 + ks) ^ arow;
        bf16x8 af = *reinterpret_cast<const bf16x8*>(&H1s[arow*512 + (chunk<<3)]);
        const __hip_bfloat16* fb = W2p + ((size_t)(kk*32 + w*4)*64 + lane)*8;
        #pragma unroll
        for (int nf=0; nf<4; ++nf)
          ac[nf] = __builtin_amdgcn_mfma_f32_16x16x32_bf16(
              af, *reinterpret_cast<const bf16x8*>(fb + nf*512), ac[nf], 0,0,0);
      }

      // epilogue: C row (lane>>4)*4 + r = bq*4 + gate; lanes 32..63 are duplicates
      if (lane < 32){
        const int a4 = lane >> 4;            // batch-local
        const int batch = B0 + a4;
        #pragma unroll
        for (int nf=0; nf<4; ++nf){
          const int n = w*64 + nf*16 + (lane & 15);
          const float fga = sigmoidf_(ac[nf][0] + bias2r[nf]);
          const float iga = sigmoidf_(ac[nf][1] + bias2r[nf]);
          const float uga = tanhf   (ac[nf][2] + bias2r[nf]);
          const float oga = sigmoidf_(ac[nf][3] + bias2r[nf]);
          const float c2 = fga*cxr[nf] + iga*uga;
          const float h2 = oga * tanhf(c2);
          cxr[nf] = c2;
          hxs[a4*512 + n] = h2;
          __builtin_nontemporal_store(h2, &out[((size_t)t*BB + batch)*HH + n]);
          if (t == TT-1){
            __builtin_nontemporal_store(h2,
                &out[(size_t)TT*BB*HH + (size_t)batch*HH + n]);
            __builtin_nontemporal_store(c2,
                &out[(size_t)TT*BB*HH + (size_t)BB*HH + (size_t)batch*HH + n]);
          }
        }
      }
    }
    __syncthreads();
  }
}

extern "C" void kernel_launch(void* const* d_in, const int* in_sizes, int n_in,
                              void* d_out, int out_size, void* d_ws, size_t ws_size,
                              hipStream_t stream)
{
  const float* x   = (const float*)d_in[0];
  const float* qpf = (const float*)d_in[1];
  const float* qpi = (const float*)d_in[2];
  const float* qpu = (const float*)d_in[3];
  const float* qpo = (const float*)d_in[4];
  const float* Wf  = (const float*)d_in[5];
  const float* bf  = (const float*)d_in[6];
  const float* Wi  = (const float*)d_in[7];
  const float* bi  = (const float*)d_in[8];
  const float* Wu  = (const float*)d_in[9];
  const float* bu  = (const float*)d_in[10];
  const float* Wo  = (const float*)d_in[11];
  const float* bo  = (const float*)d_in[12];
  const float* pW1 = (const float*)d_in[13];
  const float* pb1 = (const float*)d_in[14];
  const float* pW2 = (const float*)d_in[15];
  const float* pb2 = (const float*)d_in[16];

  float* out = (float*)d_out;
  __hip_bfloat16* W2p = (__hip_bfloat16*)d_ws;                       // 512 KB
  unsigned* pace = (unsigned*)((char*)d_ws + 524288);                // 1 KB

  (void)hipFuncSetAttribute((const void*)qlstm_all,
                            hipFuncAttributeMaxDynamicSharedMemorySize, LDS_BYTES);

  hipMemsetAsync(pace, 0, 1024, stream);
  k0_pack<<<dim3(512), dim3(64), 0, stream>>>(pW2, W2p);
  qlstm_all<<<dim3(NBLK), dim3(512), LDS_BYTES, stream>>>(
      x, Wf,Wi,Wu,Wo, bf,bi,bu,bo, qpf,qpi,qpu,qpo,
      pW1,pb1, W2p, pb2, pace, out);
}

// Round 7
// 1562.774 us; speedup vs baseline: 2.8380x; 2.0075x over previous
//
#include <hip/hip_runtime.h>
#include <hip/hip_bf16.h>
#include <math.h>

#define TT 64
#define BB 256
#define DD 512
#define HH 512
#define NBLK 256
#define LDS_BYTES 131072   // Wt[4][8][1024] f32

typedef __attribute__((ext_vector_type(8))) short bf16x8;
typedef __attribute__((ext_vector_type(4))) float f32x4;

__device__ __forceinline__ float sigmoidf_(float x){ return 1.f/(1.f+__expf(-x)); }

// ---- agent-scope coherent access helpers (correct under any XCD mapping) ----
__device__ __forceinline__ unsigned long long ld64A(const void* p){
  return __hip_atomic_load((const unsigned long long*)p, __ATOMIC_RELAXED,
                           __HIP_MEMORY_SCOPE_AGENT);
}
__device__ __forceinline__ void st64A(void* p, unsigned long long v){
  __hip_atomic_store((unsigned long long*)p, v, __ATOMIC_RELAXED,
                     __HIP_MEMORY_SCOPE_AGENT);
}
__device__ __forceinline__ void st32A(float* p, float v){
  __hip_atomic_store(p, v, __ATOMIC_RELAXED, __HIP_MEMORY_SCOPE_AGENT);
}

// ---- quantum pair helpers: amp s = lane + 64*r, r in 0..3 holds bits (7,6) ----
__device__ __forceinline__ void rx_pair(float&ra,float&ia,float&rb,float&ib,float c,float s){
  float r0=ra, i0=ia, r1=rb, i1=ib;
  ra = c*r0 + s*i1;  ia = c*i0 - s*r1;
  rb = s*i0 + c*r1;  ib = c*i1 - s*r0;
}
__device__ __forceinline__ void ry_pair(float&ra,float&ia,float&rb,float&ib,float c,float s){
  float r0=ra, i0=ia, r1=rb, i1=ib;
  ra = c*r0 - s*r1;  ia = c*i0 - s*i1;
  rb = s*r0 + c*r1;  ib = s*i0 + c*i1;
}
__device__ __forceinline__ void rz_amp(float&r,float&i,float c,float sg){
  float r0=r; r = c*r0 + sg*i; i = c*i - sg*r0;
}

// ---- one-time: pack pW2 (512x512 f32, [k][n]) into MFMA-B fragment-major bf16 ----
__global__ __launch_bounds__(64) void k0_pack(const float* __restrict__ pW2,
                                              __hip_bfloat16* __restrict__ W2p){
  const int frag = blockIdx.x;          // kk*32 + nf
  const int kk = frag >> 5, nf = frag & 31;
  const int lane = threadIdx.x;
  const int n  = nf*16 + (lane & 15);
  const int kb = kk*32 + (lane >> 4)*8;
  __hip_bfloat16 v[8];
  #pragma unroll
  for (int j=0;j<8;j++)
    v[j] = __float2bfloat16(pW2[(size_t)(kb+j)*HH + n]);
  *reinterpret_cast<uint4*>(W2p + ((size_t)frag*64 + lane)*8) =
      *reinterpret_cast<const uint4*>(v);
}

// ---- hierarchical grid barrier: 8 groups x 32 + root; load-polling ----
__device__ __forceinline__ void gridbar(unsigned* gcnt, unsigned* rcnt,
                                        unsigned* flag, int grp, unsigned ep,
                                        int tid){
  __syncthreads();                       // drains each wave's vmcnt (payload stores)
  if (tid == 0){
    __builtin_amdgcn_fence(__ATOMIC_RELEASE, "agent");   // writeback, no inv
    unsigned old = __hip_atomic_fetch_add(&gcnt[grp<<5], 1u,
                      __ATOMIC_RELAXED, __HIP_MEMORY_SCOPE_AGENT);
    if ((old & 31u) == 31u){             // last of this group's 32 arrivals
      unsigned ro = __hip_atomic_fetch_add(rcnt, 1u,
                      __ATOMIC_RELAXED, __HIP_MEMORY_SCOPE_AGENT);
      if ((ro & 7u) == 7u)               // last group overall -> release
        __hip_atomic_store(flag, ep, __ATOMIC_RELAXED, __HIP_MEMORY_SCOPE_AGENT);
    }
    while (__hip_atomic_load(flag, __ATOMIC_RELAXED,
                             __HIP_MEMORY_SCOPE_AGENT) < ep)
      __builtin_amdgcn_s_sleep(2);
  }
  __syncthreads();
}

// ---- persistent kernel: 256 blocks (1/CU), 4 waves; Q-role=batch, G-role=(mt,nt) ----
__global__ __launch_bounds__(256, 1) void qlstm_all(
    const float* __restrict__ x,
    const float* __restrict__ Wf, const float* __restrict__ Wi,
    const float* __restrict__ Wu, const float* __restrict__ Wo,
    const float* __restrict__ bfv, const float* __restrict__ biv,
    const float* __restrict__ buv, const float* __restrict__ bov,
    const float* __restrict__ qpf, const float* __restrict__ qpi,
    const float* __restrict__ qpu, const float* __restrict__ qpo,
    const float* __restrict__ pW1, const float* __restrict__ pb1,
    const __hip_bfloat16* __restrict__ W2p, const float* __restrict__ pb2,
    float* __restrict__ hxG, __hip_bfloat16* __restrict__ H1g,
    unsigned* __restrict__ bars, float* __restrict__ out)
{
  extern __shared__ float Wt[];          // [4][8][1024]

  const int tid  = threadIdx.x;
  const int lane = tid & 63;
  const int w    = tid >> 6;             // wave 0..3
  const int p    = blockIdx.x;
  const int grp  = p & 7;

  // Q role: batch (XCD-chunked), wave = gate
  const int qb = (p & 7)*32 + (p >> 3);
  // G role: (mt, nt) with same-XCD producers under round-robin dispatch
  const int mt = (p & 7)*8 + ((p >> 3) >> 2);
  const int nt = (p >> 3) & 3;

  unsigned* gcnt = bars;                  // 8 counters, 128B apart
  unsigned* rcnt = bars + 512;            // distinct line
  unsigned* flag = bars + 544;            // distinct line

  // ---- one-time LDS fill: Wt[g][q][k] = W_g[k][q] ----
  {
    const float* Ws[4] = {Wf, Wi, Wu, Wo};
    #pragma unroll
    for (int g4=0; g4<4; ++g4){
      const float* Wg_ = Ws[g4];
      for (int idx = tid; idx < 8192; idx += 256)
        Wt[g4*8192 + (idx & 7)*1024 + (idx >> 3)] = Wg_[idx];
    }
  }

  // ---- one-time register preloads ----
  const float* bias = (w==0)?bfv:(w==1)?biv:(w==2)?buv:bov;
  const float* qp   = (w==0)?qpf:(w==1)?qpi:(w==2)?qpu:qpo;
  const float* WtG  = Wt + w*8192;

  float biasr[8];
  #pragma unroll
  for (int q=0;q<8;q++) biasr[q] = bias[q];

  float cyq[16], syq[16], czq[16], szq[16];
  #pragma unroll
  for (int i=0;i<16;i++){
    __sincosf(0.5f*qp[i*3+0], &syq[i], &cyq[i]);
    __sincosf(0.5f*qp[i*3+1], &szq[i], &czq[i]);
  }

  float w1r[8][8], b1r[8];                // j = lane*8 + e layout
  #pragma unroll
  for (int e=0; e<8; ++e){
    const int j = lane*8 + e;
    b1r[e] = pb1[j];
    #pragma unroll
    for (int q=0;q<8;q++) w1r[e][q] = pW1[q*HH + j];
  }

  // G per-thread state
  const int bl    = lane >> 4;            // batch-local 0..3
  const int batch = mt*4 + bl;
  const int nc0   = nt*128 + w*32 + (lane & 15);
  const int nc1   = nc0 + 16;
  const float b2r0 = pb2[nc0], b2r1 = pb2[nc1];
  float cx0 = 0.f, cx1 = 0.f;

  __syncthreads();

  unsigned ep = 0;
  for (int t=0; t<TT; ++t){
    // ================= Phase Q: batch qb, gate w =================
    {
      float acc8[8] = {0,0,0,0,0,0,0,0};
      const float* xrow = x + ((size_t)t*BB + qb)*DD;
      #pragma unroll
      for (int it=0; it<8; ++it){
        const int k = lane + it*64;
        const float xv = xrow[k];
        #pragma unroll
        for (int q=0;q<8;q++) acc8[q] += xv * WtG[q*1024 + k];
      }
      const unsigned long long* hrow64 =
          (const unsigned long long*)(hxG + (size_t)qb*HH);
      #pragma unroll
      for (int it=0; it<4; ++it){
        const unsigned long long v = ld64A(&hrow64[lane + it*64]);
        const float h0 = __uint_as_float((unsigned)v);
        const float h1 = __uint_as_float((unsigned)(v >> 32));
        const int k = 2*(lane + it*64);
        #pragma unroll
        for (int q=0;q<8;q++)
          acc8[q] += h0*WtG[q*1024 + 512 + k] + h1*WtG[q*1024 + 512 + k + 1];
      }
      float th[8];
      #pragma unroll
      for (int q=0;q<8;q++){
        #pragma unroll
        for (int m=32;m;m>>=1) acc8[q] += __shfl_xor(acc8[q], m);
        th[q] = acc8[q] + biasr[q];
      }

      // statevector: 256 amps, lane holds s = lane + 64*r
      float re[4]={0.f,0.f,0.f,0.f}, im[4]={0.f,0.f,0.f,0.f};
      if (lane==0) re[0]=1.f;

      #pragma unroll
      for (int q=0;q<8;q++){
        float s,c; __sincosf(0.5f*th[q], &s, &c);
        if (q==0){
          rx_pair(re[0],im[0],re[2],im[2],c,s);
          rx_pair(re[1],im[1],re[3],im[3],c,s);
        } else if (q==1){
          rx_pair(re[0],im[0],re[1],im[1],c,s);
          rx_pair(re[2],im[2],re[3],im[3],c,s);
        } else {
          const int mask = 1<<(7-q);
          #pragma unroll
          for (int r=0;r<4;r++){
            float rp = __shfl_xor(re[r], mask);
            float ip = __shfl_xor(im[r], mask);
            re[r] = c*re[r] + s*ip;
            im[r] = c*im[r] - s*rp;
          }
        }
      }

      #pragma unroll
      for (int l=0;l<2;l++){
        #pragma unroll
        for (int q=0;q<8;q++){
          const float cy = cyq[l*8+q], sy = syq[l*8+q];
          if (q==0){
            ry_pair(re[0],im[0],re[2],im[2],cy,sy);
            ry_pair(re[1],im[1],re[3],im[3],cy,sy);
          } else if (q==1){
            ry_pair(re[0],im[0],re[1],im[1],cy,sy);
            ry_pair(re[2],im[2],re[3],im[3],cy,sy);
          } else {
            const int mask = 1<<(7-q);
            const float sg = (lane & mask) ? sy : -sy;
            #pragma unroll
            for (int r=0;r<4;r++){
              float rp = __shfl_xor(re[r], mask);
              float ip = __shfl_xor(im[r], mask);
              re[r] = cy*re[r] + sg*rp;
              im[r] = cy*im[r] + sg*ip;
            }
          }
          const float cz = czq[l*8+q], sz = szq[l*8+q];
          if (q==0){
            rz_amp(re[0],im[0],cz, sz); rz_amp(re[1],im[1],cz, sz);
            rz_amp(re[2],im[2],cz,-sz); rz_amp(re[3],im[3],cz,-sz);
          } else if (q==1){
            rz_amp(re[0],im[0],cz, sz); rz_amp(re[2],im[2],cz, sz);
            rz_amp(re[1],im[1],cz,-sz); rz_amp(re[3],im[3],cz,-sz);
          } else {
            const int mask = 1<<(7-q);
            const float sg = (lane & mask) ? -sz : sz;
            #pragma unroll
            for (int r=0;r<4;r++) rz_amp(re[r],im[r],cz,sg);
          }
        }
        { float tr=re[2]; re[2]=re[3]; re[3]=tr;
          float ti=im[2]; im[2]=im[3]; im[3]=ti; }
        re[1]=__shfl_xor(re[1],32); im[1]=__shfl_xor(im[1],32);
        re[3]=__shfl_xor(re[3],32); im[3]=__shfl_xor(im[3],32);
        #pragma unroll
        for (int cq=2;cq<7;cq++){
          const int cbit = 1<<(7-cq), tbit = 1<<(6-cq);
          const bool sw = (lane & cbit) != 0;
          #pragma unroll
          for (int r=0;r<4;r++){
            float rp = __shfl_xor(re[r], tbit);
            float ip = __shfl_xor(im[r], tbit);
            re[r] = sw ? rp : re[r];
            im[r] = sw ? ip : im[r];
          }
        }
      }

      // measure Z
      const float p0=re[0]*re[0]+im[0]*im[0];
      const float p1=re[1]*re[1]+im[1]*im[1];
      const float p2=re[2]*re[2]+im[2]*im[2];
      const float p3=re[3]*re[3]+im[3]*im[3];
      const float tot = p0+p1+p2+p3;
      float z[8];
      z[0] = (p0+p1)-(p2+p3);
      z[1] = (p0+p2)-(p1+p3);
      #pragma unroll
      for (int q=2;q<8;q++)
        z[q] = (lane & (1<<(7-q))) ? -tot : tot;
      #pragma unroll
      for (int q=0;q<8;q++){
        #pragma unroll
        for (int m=32;m;m>>=1) z[q] += __shfl_xor(z[q], m);
      }

      // H1 row (global, coherent): j = lane*8+e, 16B/lane coalesced
      float a[8];
      #pragma unroll
      for (int e=0;e<8;e++){
        float s = b1r[e];
        #pragma unroll
        for (int q=0;q<8;q++) s += z[q]*w1r[e][q];
        a[e] = fmaxf(s, 0.f);
      }
      union { bf16x8 v; unsigned long long u[2]; } pk;
      #pragma unroll
      for (int e=0;e<8;e++){
        __hip_bfloat16 hb = __float2bfloat16(a[e]);
        pk.v[e] = *reinterpret_cast<short*>(&hb);
      }
      unsigned long long* h1row =
          (unsigned long long*)(H1g + ((size_t)qb*4 + w)*HH) + lane*2;
      st64A(h1row,     pk.u[0]);
      st64A(h1row + 1, pk.u[1]);
    }
    gridbar(gcnt, rcnt, flag, grp, ++ep, tid);

    // ================= Phase G: tile (mt,nt): 16 rows x 128 cols =================
    {
      // A-frags: 16 kk x 16B per lane, coherent 8B loads
      bf16x8 af[16];
      {
        const int arow = mt*16 + (lane & 15);
        const unsigned long long* Ar =
            (const unsigned long long*)(H1g + (size_t)arow*HH) + (lane >> 4)*2;
        #pragma unroll
        for (int kk=0; kk<16; ++kk){
          union { bf16x8 v; unsigned long long u[2]; } t_;
          t_.u[0] = ld64A(&Ar[kk*8]);
          t_.u[1] = ld64A(&Ar[kk*8 + 1]);
          af[kk] = t_.v;
        }
      }
      f32x4 ac0 = (f32x4){0.f,0.f,0.f,0.f};
      f32x4 ac1 = (f32x4){0.f,0.f,0.f,0.f};
      const __hip_bfloat16* Wb = W2p + ((size_t)(nt*8 + w*2)*64 + lane)*8;
      #pragma unroll
      for (int kk=0; kk<16; ++kk){
        const __hip_bfloat16* fb = Wb + (size_t)kk*16384;   // kk*32 frags * 512 elems
        bf16x8 b0 = *reinterpret_cast<const bf16x8*>(fb);
        bf16x8 b1 = *reinterpret_cast<const bf16x8*>(fb + 512);
        ac0 = __builtin_amdgcn_mfma_f32_16x16x32_bf16(af[kk], b0, ac0, 0,0,0);
        ac1 = __builtin_amdgcn_mfma_f32_16x16x32_bf16(af[kk], b1, ac1, 0,0,0);
      }

      // epilogue: C reg r -> local row (lane>>4)*4 + r = batch-local*4 + gate
      {
        const float fga = sigmoidf_(ac0[0] + b2r0);
        const float iga = sigmoidf_(ac0[1] + b2r0);
        const float uga = tanhf   (ac0[2] + b2r0);
        const float oga = sigmoidf_(ac0[3] + b2r0);
        const float c2 = fga*cx0 + iga*uga;
        const float h2 = oga * tanhf(c2);
        cx0 = c2;
        st32A(&hxG[(size_t)batch*HH + nc0], h2);
        __builtin_nontemporal_store(h2, &out[((size_t)t*BB + batch)*HH + nc0]);
        if (t == TT-1){
          __builtin_nontemporal_store(h2, &out[(size_t)TT*BB*HH + (size_t)batch*HH + nc0]);
          __builtin_nontemporal_store(c2, &out[(size_t)TT*BB*HH + (size_t)BB*HH + (size_t)batch*HH + nc0]);
        }
      }
      {
        const float fga = sigmoidf_(ac1[0] + b2r1);
        const float iga = sigmoidf_(ac1[1] + b2r1);
        const float uga = tanhf   (ac1[2] + b2r1);
        const float oga = sigmoidf_(ac1[3] + b2r1);
        const float c2 = fga*cx1 + iga*uga;
        const float h2 = oga * tanhf(c2);
        cx1 = c2;
        st32A(&hxG[(size_t)batch*HH + nc1], h2);
        __builtin_nontemporal_store(h2, &out[((size_t)t*BB + batch)*HH + nc1]);
        if (t == TT-1){
          __builtin_nontemporal_store(h2, &out[(size_t)TT*BB*HH + (size_t)batch*HH + nc1]);
          __builtin_nontemporal_store(c2, &out[(size_t)TT*BB*HH + (size_t)BB*HH + (size_t)batch*HH + nc1]);
        }
      }
    }
    if (t != TT-1) gridbar(gcnt, rcnt, flag, grp, ++ep, tid);
  }
}

extern "C" void kernel_launch(void* const* d_in, const int* in_sizes, int n_in,
                              void* d_out, int out_size, void* d_ws, size_t ws_size,
                              hipStream_t stream)
{
  const float* x   = (const float*)d_in[0];
  const float* qpf = (const float*)d_in[1];
  const float* qpi = (const float*)d_in[2];
  const float* qpu = (const float*)d_in[3];
  const float* qpo = (const float*)d_in[4];
  const float* Wf  = (const float*)d_in[5];
  const float* bf  = (const float*)d_in[6];
  const float* Wi  = (const float*)d_in[7];
  const float* bi  = (const float*)d_in[8];
  const float* Wu  = (const float*)d_in[9];
  const float* bu  = (const float*)d_in[10];
  const float* Wo  = (const float*)d_in[11];
  const float* bo  = (const float*)d_in[12];
  const float* pW1 = (const float*)d_in[13];
  const float* pb1 = (const float*)d_in[14];
  const float* pW2 = (const float*)d_in[15];
  const float* pb2 = (const float*)d_in[16];

  float* out = (float*)d_out;
  __hip_bfloat16* W2p = (__hip_bfloat16*)d_ws;                       // 512 KB
  unsigned* bars = (unsigned*)((char*)d_ws + 524288);                // 4 KB
  float*    hxG  = (float*)((char*)d_ws + 524288 + 4096);            // 512 KB
  __hip_bfloat16* H1g = (__hip_bfloat16*)((char*)d_ws + 524288 + 4096 + 524288); // 1 MB

  (void)hipFuncSetAttribute((const void*)qlstm_all,
                            hipFuncAttributeMaxDynamicSharedMemorySize, LDS_BYTES);

  // zero barrier state + hx
  hipMemsetAsync((char*)d_ws + 524288, 0, 4096 + 524288, stream);
  k0_pack<<<dim3(512), dim3(64), 0, stream>>>(pW2, W2p);
  qlstm_all<<<dim3(NBLK), dim3(256), LDS_BYTES, stream>>>(
      x, Wf,Wi,Wu,Wo, bf,bi,bu,bo, qpf,qpi,qpu,qpo,
      pW1,pb1, W2p, pb2, hxG, H1g, bars, out);
}